// Round 1
// baseline (1282.612 us; speedup 1.0000x reference)
//
#include <hip/hip_runtime.h>

// ---------- constants ----------
#define NB 32        // batch
#define NT 64        // seq len
#define NE 256       // n_emb
#define NH 8         // heads
#define ND 32        // head dim
#define NL 8         // layers
#define NF 1024      // ffn hidden
#define NV 50257     // vocab
#define NVPAD 50304  // vocab padded to 128

typedef __bf16 bf16x8 __attribute__((ext_vector_type(8)));
typedef float f32x4 __attribute__((ext_vector_type(4)));

__device__ __forceinline__ float b2f(unsigned short h) {
  union { unsigned int u; float f; } c; c.u = ((unsigned int)h) << 16; return c.f;
}
__device__ __forceinline__ unsigned short f2b(float f) {
  union { float f; unsigned int u; } c; c.f = f;
  unsigned int u = c.u + 0x7FFFu + ((c.u >> 16) & 1u);
  return (unsigned short)(u >> 16);
}
// dtype-adaptive scalar load: isbf ? bf16[i] : f32[i]
__device__ __forceinline__ float ldf(const void* p, size_t i, int isbf) {
  return isbf ? b2f(((const unsigned short*)p)[i]) : ((const float*)p)[i];
}
__device__ __forceinline__ int get_isbf(const unsigned int* probe) {
  return (probe[0] == 0x3F800000u) ? 0 : 1;  // ln1_g[0] == 1.0f
}

__device__ __forceinline__ void gload16(const unsigned short* g, unsigned short* l) {
  __builtin_amdgcn_global_load_lds(
      (const __attribute__((address_space(1))) unsigned int*)g,
      (__attribute__((address_space(3))) unsigned int*)l, 16, 0, 0);
}

// ---------- merged per-layer weight transpose (Wq,Wk,Wv,Wo,W1,W2 -> bf16 [N][K]) ----------
// grid (768, 1, NL), block (32,8)
__global__ __launch_bounds__(256)
void transpose_weights_k(const void* __restrict__ Wq, const void* __restrict__ Wk,
                         const void* __restrict__ Wv, const void* __restrict__ Wo,
                         const void* __restrict__ W1, const void* __restrict__ W2,
                         const unsigned int* __restrict__ probe,
                         unsigned short* __restrict__ WqkvT, unsigned short* __restrict__ WoT,
                         unsigned short* __restrict__ W1T, unsigned short* __restrict__ W2T)
{
  __shared__ unsigned short tile[32][33];
  const int isbf = get_isbf(probe);
  const int z = blockIdx.z, x = blockIdx.x;
  const void* src; unsigned short* dst; int K, N, k0, n0;
  size_t soff, doff;
  if (x < 192) {                      // Wq/Wk/Wv: per (l,h) [256][32]
    const int t = x >> 6, r = x & 63, h = r >> 3, ky = r & 7;
    src = (t == 0) ? Wq : ((t == 1) ? Wk : Wv);
    soff = (size_t)z * 65536 + (size_t)h * 8192; K = 256; N = 32; k0 = ky * 32; n0 = 0;
    dst = WqkvT; doff = (size_t)z * 196608 + (size_t)(t * 256 + h * 32) * 256;
  } else if (x < 256) {               // Wo [256][256]
    const int r = x - 192, ny = r >> 3, ky = r & 7;
    src = Wo; soff = (size_t)z * 65536; K = 256; N = 256; k0 = ky * 32; n0 = ny * 32;
    dst = WoT; doff = (size_t)z * 65536;
  } else if (x < 512) {               // W1 [256][1024]
    const int r = x - 256, ny = r >> 3, ky = r & 7;
    src = W1; soff = (size_t)z * 262144; K = 256; N = 1024; k0 = ky * 32; n0 = ny * 32;
    dst = W1T; doff = (size_t)z * 262144;
  } else {                            // W2 [1024][256]
    const int r = x - 512, ky = r >> 3, ny = r & 7;
    src = W2; soff = (size_t)z * 262144; K = 1024; N = 256; k0 = ky * 32; n0 = ny * 32;
    dst = W2T; doff = (size_t)z * 262144;
  }
  const int tx = threadIdx.x, ty = threadIdx.y;
#pragma unroll
  for (int i = 0; i < 4; ++i) {
    const int k = k0 + ty + i * 8, n = n0 + tx;
    tile[ty + i * 8][tx] = f2b(ldf(src, soff + (size_t)k * N + n, isbf));
  }
  __syncthreads();
#pragma unroll
  for (int i = 0; i < 4; ++i) {
    const int n = n0 + ty + i * 8, k = k0 + tx;
    dst[doff + (size_t)n * K + k] = tile[tx][ty + i * 8];
  }
}

// ---------- guarded transpose for Wlm: dst[n][k] = src[k][n] ----------
__global__ __launch_bounds__(256)
void transpose_k(const void* __restrict__ srcv, unsigned short* __restrict__ dst,
                 const unsigned int* __restrict__ probe, int K, int N)
{
  __shared__ unsigned short tile[32][33];
  const int isbf = get_isbf(probe);
  const int n0 = blockIdx.x * 32, k0 = blockIdx.y * 32;
  const int tx = threadIdx.x, ty = threadIdx.y;
#pragma unroll
  for (int i = 0; i < 4; ++i) {
    const int k = k0 + ty + i * 8, n = n0 + tx;
    if (k < K && n < N)
      tile[ty + i * 8][tx] = f2b(ldf(srcv, (size_t)k * N + n, isbf));
  }
  __syncthreads();
#pragma unroll
  for (int i = 0; i < 4; ++i) {
    const int n = n0 + ty + i * 8, k = k0 + tx;
    if (n < N && k < K) dst[(size_t)n * K + k] = tile[tx][ty + i * 8];
  }
}

// ---------- embedding: x = tok_emb[ip] + pos_emb ----------
__global__ __launch_bounds__(256)
void embed_k(const int* __restrict__ ip, const void* __restrict__ te,
             const void* __restrict__ pe, const unsigned int* __restrict__ probe,
             float* __restrict__ x, unsigned short* __restrict__ xb)
{
  const int isbf = get_isbf(probe);
  const int i = blockIdx.x * 256 + threadIdx.x;   // over 2048*256
  const int tp = i >> 8, e = i & 255, t = tp & (NT - 1);
  const int id = ip[tp];
  float v = ldf(te, (size_t)id * NE + e, isbf) + ldf(pe, (size_t)t * NE + e, isbf);
  x[i] = v;
  xb[i] = f2b(v);
}

// ---------- generic MFMA GEMM: C[M][N] = A[M][K] * BT[N][K]^T (+bias)(+relu) ----------
// OUTMODE: 0 = bf16, 1 = f32, 2 = adaptive (match input dtype)
template<int BM, int BN, int BK, int WM, int WN, bool BIAS, bool RELU, int OUTMODE>
__global__ __launch_bounds__(256)
void gemm_bt(const unsigned short* __restrict__ A, const unsigned short* __restrict__ BT,
             const void* __restrict__ bias, int boff, const unsigned int* __restrict__ probe,
             void* __restrict__ Cv, int M, int N, int K, int ldc)
{
  static_assert((BM / WM) * (BN / WN) == 4, "4 waves");
  static_assert(BK == 64, "BK=64");
  __shared__ __align__(16) unsigned short As[BM * BK];
  __shared__ __align__(16) unsigned short Bs[BN * BK];
  const int tid = threadIdx.x;
  const int lane = tid & 63;
  const int wave = tid >> 6;
  const int m0 = blockIdx.y * BM;
  const int n0 = blockIdx.x * BN;
  constexpr int WAVES_N = BN / WN;
  const int wm = (wave / WAVES_N) * WM;
  const int wn = (wave % WAVES_N) * WN;
  constexpr int MT = WM / 16;
  constexpr int NTt = WN / 16;
  f32x4 acc[MT][NTt] = {};

  constexpr int AITERS = (BM * BK) / 2048;
  constexpr int BITERS = (BN * BK) / 2048;
  const int srow = tid >> 3;            // [0,32)
  const int scol = (tid & 7) * 8;       // element col within BK
  const int lc = lane & 15;
  const int lk = (lane >> 4) * 8;
  const int lr = (lane >> 4) * 4;

  for (int k0 = 0; k0 < K; k0 += BK) {
#pragma unroll
    for (int it = 0; it < AITERS; ++it)
      gload16(A + (size_t)(m0 + it * 32 + srow) * K + (k0 + scol), &As[it * 2048 + wave * 512]);
#pragma unroll
    for (int it = 0; it < BITERS; ++it)
      gload16(BT + (size_t)(n0 + it * 32 + srow) * K + (k0 + scol), &Bs[it * 2048 + wave * 512]);
    __syncthreads();
#pragma unroll
    for (int ks = 0; ks < BK; ks += 32) {
      bf16x8 afr[MT], bfr[NTt];
#pragma unroll
      for (int i = 0; i < MT; ++i)
        afr[i] = *(const bf16x8*)&As[(wm + i * 16 + lc) * BK + ks + lk];
#pragma unroll
      for (int j = 0; j < NTt; ++j)
        bfr[j] = *(const bf16x8*)&Bs[(wn + j * 16 + lc) * BK + ks + lk];
#pragma unroll
      for (int i = 0; i < MT; ++i)
#pragma unroll
        for (int j = 0; j < NTt; ++j)
          acc[i][j] = __builtin_amdgcn_mfma_f32_16x16x32_bf16(afr[i], bfr[j], acc[i][j], 0, 0, 0);
    }
    __syncthreads();
  }

  int isbf = 1;
  if constexpr (BIAS || OUTMODE == 2) isbf = get_isbf(probe);
#pragma unroll
  for (int i = 0; i < MT; ++i) {
#pragma unroll
    for (int j = 0; j < NTt; ++j) {
      const int col = n0 + wn + j * 16 + lc;
      if (col < N) {
        float bv = BIAS ? ldf(bias, (size_t)(boff + col), isbf) : 0.0f;
#pragma unroll
        for (int q = 0; q < 4; ++q) {
          const int row = m0 + wm + i * 16 + lr + q;
          float v = acc[i][j][q] + bv;
          if (RELU) v = fmaxf(v, 0.0f);
          const size_t idx = (size_t)row * ldc + col;
          if (OUTMODE == 1) ((float*)Cv)[idx] = v;
          else if (OUTMODE == 0) ((unsigned short*)Cv)[idx] = f2b(v);
          else { if (isbf) ((unsigned short*)Cv)[idx] = f2b(v); else ((float*)Cv)[idx] = v; }
        }
      }
    }
  }
}

// ---------- fused QKV projection + causal attention ----------
// one block per (b,h); 4 waves. QKV via direct-global MFMA (operands L2-hot),
// f32 q/k/v into LDS, then wave-strip online-softmax attention.
__global__ __launch_bounds__(256)
void qkv_attn_k(const unsigned short* __restrict__ xb, const unsigned short* __restrict__ Wl,
                unsigned short* __restrict__ att)
{
  const int bh = blockIdx.x, bb = bh >> 3, h = bh & 7;
  __shared__ float Q[NT][ND], Kc[NT][ND], Vc[NT][ND];
  __shared__ float pm[4][NT], pl[4][NT];
  __shared__ float pacc[4][NT][ND + 1];
  const int tid = threadIdx.x, wv = tid >> 6, l = tid & 63;
  const int lc = l & 15, lk = (l >> 4) * 8, lr = (l >> 4) * 4;

  // ---- QKV: out rows (this wave) = wv*16..wv*16+15, cols 0..95 (q|k|v) ----
  f32x4 acc6[6] = {};
  const unsigned short* Arow = xb + (size_t)(bb * NT + wv * 16 + lc) * NE + lk;
  const unsigned short* B0 = Wl + (size_t)(h * ND + lc) * NE + lk;
#pragma unroll 2
  for (int k0 = 0; k0 < NE; k0 += 32) {
    bf16x8 afr = *(const bf16x8*)(Arow + k0);
#pragma unroll
    for (int j = 0; j < 6; ++j) {
      const bf16x8 bfr = *(const bf16x8*)(B0 + (size_t)((j >> 1) * 256 + (j & 1) * 16) * NE + k0);
      acc6[j] = __builtin_amdgcn_mfma_f32_16x16x32_bf16(afr, bfr, acc6[j], 0, 0, 0);
    }
  }
#pragma unroll
  for (int j = 0; j < 6; ++j) {
    float* dst = (j >> 1) == 0 ? &Q[0][0] : ((j >> 1) == 1 ? &Kc[0][0] : &Vc[0][0]);
    const int col = (j & 1) * 16 + lc;
#pragma unroll
    for (int qq = 0; qq < 4; ++qq) {
      const int row = wv * 16 + lr + qq;
      dst[row * ND + col] = acc6[j][qq];
    }
  }
  __syncthreads();

  // ---- attention: lane t owns query row t; wave wv owns key strip [wv*16, wv*16+16) ----
  const int t = l;
  float q[ND];
#pragma unroll
  for (int d = 0; d < ND; ++d) q[d] = Q[t][d] * 0.17677669529663689f; // 1/sqrt(32)
  const int s0 = wv * 16;
  const int s1 = min(s0 + 16, t + 1);
  float mx = -1e30f;
  for (int s = s0; s < s1; ++s) {
    const float4* kp = (const float4*)&Kc[s][0];
    float dot = 0.0f;
#pragma unroll
    for (int c = 0; c < 8; ++c) {
      const float4 kv = kp[c];
      dot += q[c*4+0]*kv.x + q[c*4+1]*kv.y + q[c*4+2]*kv.z + q[c*4+3]*kv.w;
    }
    mx = fmaxf(mx, dot);
  }
  float sum = 0.0f;
  float acc[ND] = {};
  for (int s = s0; s < s1; ++s) {
    const float4* kp = (const float4*)&Kc[s][0];
    float dot = 0.0f;
#pragma unroll
    for (int c = 0; c < 8; ++c) {
      const float4 kv = kp[c];
      dot += q[c*4+0]*kv.x + q[c*4+1]*kv.y + q[c*4+2]*kv.z + q[c*4+3]*kv.w;
    }
    const float e = __expf(dot - mx);
    sum += e;
    const float4* vp = (const float4*)&Vc[s][0];
#pragma unroll
    for (int c = 0; c < 8; ++c) {
      const float4 vv = vp[c];
      acc[c*4+0] += e*vv.x; acc[c*4+1] += e*vv.y; acc[c*4+2] += e*vv.z; acc[c*4+3] += e*vv.w;
    }
  }
  pm[wv][t] = mx; pl[wv][t] = sum;
#pragma unroll
  for (int d = 0; d < ND; ++d) pacc[wv][t][d] = acc[d];
  __syncthreads();

  // merge 4 partials: thread -> (t = tid>>2, d-range (tid&3)*8..+8)
  const int mt = tid >> 2, jj = tid & 3;
  float M = -1e30f;
#pragma unroll
  for (int w = 0; w < 4; ++w) M = fmaxf(M, pm[w][mt]);
  float ew[4], L = 0.0f;
#pragma unroll
  for (int w = 0; w < 4; ++w) { ew[w] = __expf(pm[w][mt] - M); L += pl[w][mt] * ew[w]; }
  const float inv = 1.0f / L;
  unsigned short* op = att + (size_t)(bb * NT + mt) * NE + h * ND + jj * 8;
#pragma unroll
  for (int dd = 0; dd < 8; ++dd) {
    float o = 0.0f;
#pragma unroll
    for (int w = 0; w < 4; ++w) o += pacc[w][mt][jj * 8 + dd] * ew[w];
    op[dd] = f2b(o * inv);
  }
}

// ---------- fused GEMM (BM=16, full 256-col row) + bias + residual + LayerNorm ----------
// Direct-global MFMA fragments (operands are L2-resident), no staging barriers.
// A [2048][K] bf16, BT [256][K] bf16; out: x (f32) and xb (bf16), both [2048][256]
__global__ __launch_bounds__(256)
void gemm_ln_k(const unsigned short* __restrict__ A, const unsigned short* __restrict__ BT,
               const void* __restrict__ bias, int boff,
               const void* __restrict__ g, const void* __restrict__ b, int goff,
               const unsigned int* __restrict__ probe, const float* __restrict__ xres,
               float* __restrict__ xout, unsigned short* __restrict__ xbout, int K)
{
  __shared__ float vbuf[16][257];
  const int isbf = get_isbf(probe);
  const int tid = threadIdx.x, lane = tid & 63, wave = tid >> 6;
  const int m0 = blockIdx.x * 16;
  const int wn = wave * 64;
  const int lc = lane & 15, lk = (lane >> 4) * 8, lr = (lane >> 4) * 4;
  f32x4 acc[4] = {};

  const unsigned short* Arow = A + (size_t)(m0 + lc) * K + lk;
  const unsigned short* Brow = BT + (size_t)(wn + lc) * K + lk;
#pragma unroll 4
  for (int k0 = 0; k0 < K; k0 += 32) {
    const bf16x8 afr = *(const bf16x8*)(Arow + k0);
#pragma unroll
    for (int j = 0; j < 4; ++j) {
      const bf16x8 bfr = *(const bf16x8*)(Brow + (size_t)j * 16 * K + k0);
      acc[j] = __builtin_amdgcn_mfma_f32_16x16x32_bf16(afr, bfr, acc[j], 0, 0, 0);
    }
  }

  // v = acc + bias + residual -> LDS
#pragma unroll
  for (int j = 0; j < 4; ++j) {
    const int col = wn + j * 16 + lc;
    const float bv = ldf(bias, (size_t)(boff + col), isbf);
#pragma unroll
    for (int qq = 0; qq < 4; ++qq) {
      const int row = lr + qq;
      vbuf[row][col] = acc[j][qq] + bv + xres[(size_t)(m0 + row) * NE + col];
    }
  }
  __syncthreads();

  // per-row LN: team of 16 threads per row
  const int row = tid >> 4, lo = tid & 15;
  float s = 0.0f, s2 = 0.0f;
  for (int c = lo; c < 256; c += 16) { const float v = vbuf[row][c]; s += v; s2 += v * v; }
#pragma unroll
  for (int off = 8; off > 0; off >>= 1) { s += __shfl_xor(s, off); s2 += __shfl_xor(s2, off); }
  const float m = s * (1.0f / NE);
  const float var = s2 * (1.0f / NE) - m * m;
  const float r = rsqrtf(var + 1e-5f);
  for (int c = lo; c < 256; c += 16) {
    const float o = (vbuf[row][c] - m) * r * ldf(g, (size_t)(goff + c), isbf)
                    + ldf(b, (size_t)(goff + c), isbf);
    const size_t idx = (size_t)(m0 + row) * NE + c;
    xout[idx] = o;
    xbout[idx] = f2b(o);
  }
}

// ---------- final LayerNorm (no residual): x f32 -> xf bf16 ----------
__global__ __launch_bounds__(256)
void lnf_k(const float* __restrict__ xin, const void* __restrict__ gv,
           const void* __restrict__ bv, const unsigned int* __restrict__ probe,
           unsigned short* __restrict__ xout_b)
{
  const int isbf = get_isbf(probe);
  const int tok = blockIdx.x, e = threadIdx.x;
  const float v = xin[tok * NE + e];
  float s = v, s2 = v * v;
#pragma unroll
  for (int off = 32; off > 0; off >>= 1) {
    s  += __shfl_down(s, off);
    s2 += __shfl_down(s2, off);
  }
  __shared__ float red[10];
  const int wv = e >> 6, ln = e & 63;
  if (ln == 0) { red[wv] = s; red[4 + wv] = s2; }
  __syncthreads();
  if (e == 0) {
    const float ts = red[0] + red[1] + red[2] + red[3];
    const float t2 = red[4] + red[5] + red[6] + red[7];
    const float m = ts * (1.0f / NE);
    const float var = t2 * (1.0f / NE) - m * m;
    red[8] = m; red[9] = rsqrtf(var + 1e-5f);
  }
  __syncthreads();
  const float m = red[8], r = red[9];
  const float o = (v - m) * r * ldf(gv, (size_t)e, isbf) + ldf(bv, (size_t)e, isbf);
  xout_b[tok * NE + e] = f2b(o);
}

// ---------- host orchestration ----------
extern "C" void kernel_launch(void* const* d_in, const int* in_sizes, int n_in,
                              void* d_out, int out_size, void* d_ws, size_t ws_size,
                              hipStream_t stream) {
  const int* ip = (const int*)d_in[0];
  const void* tok_emb = d_in[1];
  const void* pos_emb = d_in[2];
  const void* Wq = d_in[3];
  const void* Wk = d_in[4];
  const void* Wv = d_in[5];
  const void* Wo = d_in[6];
  const void* bo = d_in[7];
  const void* ln1_g = d_in[8];
  const void* ln1_b = d_in[9];
  const void* ln2_g = d_in[10];
  const void* ln2_b = d_in[11];
  const void* W1 = d_in[12];
  const void* b1 = d_in[13];
  const void* W2 = d_in[14];
  const void* b2 = d_in[15];
  const void* lnf_g = d_in[16];
  const void* lnf_b = d_in[17];
  const void* Wlm = d_in[18];
  const void* blm = d_in[19];
  const unsigned int* probe = (const unsigned int*)ln1_g;

  const int M = NB * NT; // 2048 tokens

  // ---- workspace layout ----
  unsigned short* xb   = (unsigned short*)d_ws;            // [2048][256]
  unsigned short* xf   = xb   + (size_t)M * NE;            // [2048][256]
  unsigned short* att  = xf   + (size_t)M * NE;            // [2048][256]
  unsigned short* hbuf = att  + (size_t)M * NE;            // [2048][1024]
  float*          x    = (float*)(hbuf + (size_t)M * NF);  // [2048][256] f32
  unsigned short* WqkvT = (unsigned short*)(x + (size_t)M * NE); // [L][768][256]
  unsigned short* WoT  = WqkvT + (size_t)NL * 768 * NE;    // [L][256][256]
  unsigned short* W1T  = WoT   + (size_t)NL * NE * NE;     // [L][1024][256]
  unsigned short* W2T  = W1T   + (size_t)NL * NF * NE;     // [L][256][1024]
  unsigned short* WlmT = W2T   + (size_t)NL * NE * NF;     // [NVPAD][256]

  // ---- weight transposes (2 launches) ----
  dim3 tb(32, 8, 1);
  transpose_weights_k<<<dim3(768, 1, NL), tb, 0, stream>>>(
      Wq, Wk, Wv, Wo, W1, W2, probe, WqkvT, WoT, W1T, W2T);
  transpose_k<<<dim3((NV + 31) / 32, NE / 32, 1), tb, 0, stream>>>(Wlm, WlmT, probe, NE, NV);

  // ---- embedding ----
  embed_k<<<dim3(M), dim3(256), 0, stream>>>(ip, tok_emb, pos_emb, probe, x, xb);

  // ---- transformer layers ----
  for (int l = 0; l < NL; ++l) {
    // fused QKV projection + attention: one block per (b,h)
    qkv_attn_k<<<dim3(NB * NH), dim3(256), 0, stream>>>(
        xb, WqkvT + (size_t)l * 768 * NE, att);
    // x = LN(x + att*Wo + bo)
    gemm_ln_k<<<dim3(M / 16), dim3(256), 0, stream>>>(
        att, WoT + (size_t)l * NE * NE, bo, l * NE, ln1_g, ln1_b, l * NE,
        probe, x, x, xb, NE);
    // FFN1: relu(xb W1 + b1) -> hbuf (bf16)
    gemm_bt<64, 64, 64, 32, 32, true, true, 0><<<dim3(NF / 64, M / 64), dim3(256), 0, stream>>>(
        xb, W1T + (size_t)l * NF * NE, b1, l * NF, probe, hbuf, M, NF, NE, NF);
    // x = LN(x + hbuf*W2 + b2)
    gemm_ln_k<<<dim3(M / 16), dim3(256), 0, stream>>>(
        hbuf, W2T + (size_t)l * NE * NF, b2, l * NE, ln2_g, ln2_b, l * NE,
        probe, x, x, xb, NF);
  }

  // ---- final LN -> xf (bf16) ----
  lnf_k<<<dim3(M), dim3(256), 0, stream>>>(x, lnf_g, lnf_b, probe, xf);

  // ---- LM head: xf [2048,256] x WlmT + blm -> out (dtype-adaptive) ----
  gemm_bt<128, 128, 64, 64, 64, true, false, 2><<<dim3(NVPAD / 128, M / 128), dim3(256), 0, stream>>>(
      xf, WlmT, blm, 0, probe, d_out, M, NV, NE, NV);
}

// Round 3
// 1194.580 us; speedup vs baseline: 1.0737x; 1.0737x over previous
//
#include <hip/hip_runtime.h>

// ---------- constants ----------
#define NB 32        // batch
#define NT 64        // seq len
#define NE 256       // n_emb
#define NH 8         // heads
#define ND 32        // head dim
#define NL 8         // layers
#define NF 1024      // ffn hidden
#define NV 50257     // vocab
#define NVPAD 50304  // vocab padded to 128

typedef __bf16 bf16x8 __attribute__((ext_vector_type(8)));
typedef float f32x4 __attribute__((ext_vector_type(4)));

__device__ __forceinline__ float b2f(unsigned short h) {
  union { unsigned int u; float f; } c; c.u = ((unsigned int)h) << 16; return c.f;
}
__device__ __forceinline__ unsigned short f2b(float f) {
  union { float f; unsigned int u; } c; c.f = f;
  unsigned int u = c.u + 0x7FFFu + ((c.u >> 16) & 1u);
  return (unsigned short)(u >> 16);
}
// dtype-adaptive scalar load: isbf ? bf16[i] : f32[i]
__device__ __forceinline__ float ldf(const void* p, size_t i, int isbf) {
  return isbf ? b2f(((const unsigned short*)p)[i]) : ((const float*)p)[i];
}
__device__ __forceinline__ int get_isbf(const unsigned int* probe) {
  return (probe[0] == 0x3F800000u) ? 0 : 1;  // ln1_g[0] == 1.0f
}

__device__ __forceinline__ void gload16(const unsigned short* g, unsigned short* l) {
  __builtin_amdgcn_global_load_lds(
      (const __attribute__((address_space(1))) unsigned int*)g,
      (__attribute__((address_space(3))) unsigned int*)l, 16, 0, 0);
}

// ---------- merged per-layer weight transpose (Wq,Wk,Wv,Wo,W1,W2 -> bf16 [N][K]) ----------
// grid (768, 1, NL), block (32,8)
__global__ __launch_bounds__(256)
void transpose_weights_k(const void* __restrict__ Wq, const void* __restrict__ Wk,
                         const void* __restrict__ Wv, const void* __restrict__ Wo,
                         const void* __restrict__ W1, const void* __restrict__ W2,
                         const unsigned int* __restrict__ probe,
                         unsigned short* __restrict__ WqkvT, unsigned short* __restrict__ WoT,
                         unsigned short* __restrict__ W1T, unsigned short* __restrict__ W2T)
{
  __shared__ unsigned short tile[32][33];
  const int isbf = get_isbf(probe);
  const int z = blockIdx.z, x = blockIdx.x;
  const void* src; unsigned short* dst; int K, N, k0, n0;
  size_t soff, doff;
  if (x < 192) {                      // Wq/Wk/Wv: per (l,h) [256][32]
    const int t = x >> 6, r = x & 63, h = r >> 3, ky = r & 7;
    src = (t == 0) ? Wq : ((t == 1) ? Wk : Wv);
    soff = (size_t)z * 65536 + (size_t)h * 8192; K = 256; N = 32; k0 = ky * 32; n0 = 0;
    dst = WqkvT; doff = (size_t)z * 196608 + (size_t)(t * 256 + h * 32) * 256;
  } else if (x < 256) {               // Wo [256][256]
    const int r = x - 192, ny = r >> 3, ky = r & 7;
    src = Wo; soff = (size_t)z * 65536; K = 256; N = 256; k0 = ky * 32; n0 = ny * 32;
    dst = WoT; doff = (size_t)z * 65536;
  } else if (x < 512) {               // W1 [256][1024]
    const int r = x - 256, ny = r >> 3, ky = r & 7;
    src = W1; soff = (size_t)z * 262144; K = 256; N = 1024; k0 = ky * 32; n0 = ny * 32;
    dst = W1T; doff = (size_t)z * 262144;
  } else {                            // W2 [1024][256]
    const int r = x - 512, ky = r >> 3, ny = r & 7;
    src = W2; soff = (size_t)z * 262144; K = 1024; N = 256; k0 = ky * 32; n0 = ny * 32;
    dst = W2T; doff = (size_t)z * 262144;
  }
  const int tx = threadIdx.x, ty = threadIdx.y;
#pragma unroll
  for (int i = 0; i < 4; ++i) {
    const int k = k0 + ty + i * 8, n = n0 + tx;
    tile[ty + i * 8][tx] = f2b(ldf(src, soff + (size_t)k * N + n, isbf));
  }
  __syncthreads();
#pragma unroll
  for (int i = 0; i < 4; ++i) {
    const int n = n0 + ty + i * 8, k = k0 + tx;
    dst[doff + (size_t)n * K + k] = tile[tx][ty + i * 8];
  }
}

// ---------- guarded transpose for Wlm: dst[n][k] = src[k][n] ----------
__global__ __launch_bounds__(256)
void transpose_k(const void* __restrict__ srcv, unsigned short* __restrict__ dst,
                 const unsigned int* __restrict__ probe, int K, int N)
{
  __shared__ unsigned short tile[32][33];
  const int isbf = get_isbf(probe);
  const int n0 = blockIdx.x * 32, k0 = blockIdx.y * 32;
  const int tx = threadIdx.x, ty = threadIdx.y;
#pragma unroll
  for (int i = 0; i < 4; ++i) {
    const int k = k0 + ty + i * 8, n = n0 + tx;
    if (k < K && n < N)
      tile[ty + i * 8][tx] = f2b(ldf(srcv, (size_t)k * N + n, isbf));
  }
  __syncthreads();
#pragma unroll
  for (int i = 0; i < 4; ++i) {
    const int n = n0 + ty + i * 8, k = k0 + tx;
    if (n < N && k < K) dst[(size_t)n * K + k] = tile[tx][ty + i * 8];
  }
}

// ---------- embedding: x = tok_emb[ip] + pos_emb ----------
__global__ __launch_bounds__(256)
void embed_k(const int* __restrict__ ip, const void* __restrict__ te,
             const void* __restrict__ pe, const unsigned int* __restrict__ probe,
             float* __restrict__ x, unsigned short* __restrict__ xb)
{
  const int isbf = get_isbf(probe);
  const int i = blockIdx.x * 256 + threadIdx.x;   // over 2048*256
  const int tp = i >> 8, e = i & 255, t = tp & (NT - 1);
  const int id = ip[tp];
  float v = ldf(te, (size_t)id * NE + e, isbf) + ldf(pe, (size_t)t * NE + e, isbf);
  x[i] = v;
  xb[i] = f2b(v);
}

// ---------- generic MFMA GEMM: C[M][N] = A[M][K] * BT[N][K]^T (+bias)(+relu) ----------
// OUTMODE: 0 = bf16, 1 = f32, 2 = adaptive (match input dtype)
template<int BM, int BN, int BK, int WM, int WN, bool BIAS, bool RELU, int OUTMODE>
__global__ __launch_bounds__(256)
void gemm_bt(const unsigned short* __restrict__ A, const unsigned short* __restrict__ BT,
             const void* __restrict__ bias, int boff, const unsigned int* __restrict__ probe,
             void* __restrict__ Cv, int M, int N, int K, int ldc)
{
  static_assert((BM / WM) * (BN / WN) == 4, "4 waves");
  static_assert(BK == 64, "BK=64");
  __shared__ __align__(16) unsigned short As[BM * BK];
  __shared__ __align__(16) unsigned short Bs[BN * BK];
  const int tid = threadIdx.x;
  const int lane = tid & 63;
  const int wave = tid >> 6;
  const int m0 = blockIdx.y * BM;
  const int n0 = blockIdx.x * BN;
  constexpr int WAVES_N = BN / WN;
  const int wm = (wave / WAVES_N) * WM;
  const int wn = (wave % WAVES_N) * WN;
  constexpr int MT = WM / 16;
  constexpr int NTt = WN / 16;
  f32x4 acc[MT][NTt] = {};

  constexpr int AITERS = (BM * BK) / 2048;
  constexpr int BITERS = (BN * BK) / 2048;
  const int srow = tid >> 3;            // [0,32)
  const int scol = (tid & 7) * 8;       // element col within BK
  const int lc = lane & 15;
  const int lk = (lane >> 4) * 8;
  const int lr = (lane >> 4) * 4;

  for (int k0 = 0; k0 < K; k0 += BK) {
#pragma unroll
    for (int it = 0; it < AITERS; ++it)
      gload16(A + (size_t)(m0 + it * 32 + srow) * K + (k0 + scol), &As[it * 2048 + wave * 512]);
#pragma unroll
    for (int it = 0; it < BITERS; ++it)
      gload16(BT + (size_t)(n0 + it * 32 + srow) * K + (k0 + scol), &Bs[it * 2048 + wave * 512]);
    __syncthreads();
#pragma unroll
    for (int ks = 0; ks < BK; ks += 32) {
      bf16x8 afr[MT], bfr[NTt];
#pragma unroll
      for (int i = 0; i < MT; ++i)
        afr[i] = *(const bf16x8*)&As[(wm + i * 16 + lc) * BK + ks + lk];
#pragma unroll
      for (int j = 0; j < NTt; ++j)
        bfr[j] = *(const bf16x8*)&Bs[(wn + j * 16 + lc) * BK + ks + lk];
#pragma unroll
      for (int i = 0; i < MT; ++i)
#pragma unroll
        for (int j = 0; j < NTt; ++j)
          acc[i][j] = __builtin_amdgcn_mfma_f32_16x16x32_bf16(afr[i], bfr[j], acc[i][j], 0, 0, 0);
    }
    __syncthreads();
  }

  int isbf = 1;
  if constexpr (BIAS || OUTMODE == 2) isbf = get_isbf(probe);
#pragma unroll
  for (int i = 0; i < MT; ++i) {
#pragma unroll
    for (int j = 0; j < NTt; ++j) {
      const int col = n0 + wn + j * 16 + lc;
      if (col < N) {
        float bv = BIAS ? ldf(bias, (size_t)(boff + col), isbf) : 0.0f;
#pragma unroll
        for (int q = 0; q < 4; ++q) {
          const int row = m0 + wm + i * 16 + lr + q;
          float v = acc[i][j][q] + bv;
          if (RELU) v = fmaxf(v, 0.0f);
          const size_t idx = (size_t)row * ldc + col;
          if (OUTMODE == 1) ((float*)Cv)[idx] = v;
          else if (OUTMODE == 0) ((unsigned short*)Cv)[idx] = f2b(v);
          else { if (isbf) ((unsigned short*)Cv)[idx] = f2b(v); else ((float*)Cv)[idx] = v; }
        }
      }
    }
  }
}

// ---------- whole transformer layer, one block per (batch, quarter) ----------
// Block (b,i): owns tokens [i*16, i*16+16). Computes K/V for [0, i*16+16) itself
// (causal => that's all it needs). 512 threads = 8 waves.
// Phases: QKV gemm -> MFMA attention -> proj+LN1 -> FFN1 -> FFN2+LN2, all in-block.
__global__ __launch_bounds__(512)
void layer_k(const unsigned short* __restrict__ xbin, unsigned short* __restrict__ xbout,
             float* __restrict__ xg,
             const unsigned short* __restrict__ Wqkv, const unsigned short* __restrict__ Wo,
             const unsigned short* __restrict__ W1, const unsigned short* __restrict__ W2,
             const void* __restrict__ bov, const void* __restrict__ b1v, const void* __restrict__ b2v,
             const void* __restrict__ g1, const void* __restrict__ be1,
             const void* __restrict__ g2, const void* __restrict__ be2,
             const unsigned int* __restrict__ probe,
             int boffo, int boff1, int boff2, int goff)
{
  const int i = blockIdx.x, b = blockIdx.y;
  const int T0 = i * 16, ntK = i + 1;
  const int tid = threadIdx.x, lane = tid & 63, wave = tid >> 6;
  const int lc = lane & 15, l4 = lane >> 4, lk = l4 * 8, lr = l4 * 4;
  const int isbf = get_isbf(probe);

  // ---- LDS union (122880 B total, 1 block/CU) ----
  // region1 (phases A,B): Ks[64][264] bf16 @0 (33792), Vt[256][72] bf16 @33792 (36864),
  //                       Qs[16][264] bf16 @70656 (8448), Ps[8*16][72] bf16 @79104 (18432)
  // region2 (C,D,E):      xbo[16][264] bf16 @0 (8448), hs[16][1032] bf16 @8448 (33024)
  // persistent:           atts[16][264] bf16 @97536 (8448), xs[16][264] f32 @105984 (16896)
  __shared__ __align__(16) char smem[122880];
  unsigned short (*Ks)[264]   = (unsigned short(*)[264])(smem);
  unsigned short (*Vt)[72]    = (unsigned short(*)[72])(smem + 33792);
  unsigned short (*Qs)[264]   = (unsigned short(*)[264])(smem + 70656);
  unsigned short (*Ps)[72]    = (unsigned short(*)[72])(smem + 79104);
  unsigned short (*xbo)[264]  = (unsigned short(*)[264])(smem);
  unsigned short (*hs)[1032]  = (unsigned short(*)[1032])(smem + 8448);
  unsigned short (*atts)[264] = (unsigned short(*)[264])(smem + 97536);
  float (*xs)[264]            = (float(*)[264])(smem + 105984);

  // ---- zero Vt so PV over padded/garbage keys is exactly 0 ----
  {
    int* vz = (int*)(smem + 33792);
    for (int jj = tid; jj < 36864 / 4; jj += 512) vz[jj] = 0;
  }
  __syncthreads();

  // ================= Phase A: QKV GEMM =================
  // K/V: out rows [0,qend), cols 512 (K|V); wave w -> 64-col slice.
  // Q: out rows [T0,T0+16), 256 cols; wave w -> 32-col slice.
  {
    f32x4 aKV[4][4] = {};
    f32x4 aQ[2] = {};
    const unsigned short* Ab = xbin + ((size_t)(b * 64 + lc)) * NE + lk;
    const int nKV = wave * 64;
    const int nQ0 = wave * 32;
#pragma unroll
    for (int ks = 0; ks < 8; ++ks) {
      const int k0 = ks * 32;
      bf16x8 afr[4];
#pragma unroll
      for (int mt = 0; mt < 4; ++mt)
        if (mt <= i) afr[mt] = *(const bf16x8*)(Ab + (size_t)mt * 16 * NE + k0);
#pragma unroll
      for (int nt = 0; nt < 4; ++nt) {
        const bf16x8 bkv = *(const bf16x8*)(Wqkv + (size_t)(256 + nKV + nt * 16 + lc) * NE + k0 + lk);
#pragma unroll
        for (int mt = 0; mt < 4; ++mt)
          if (mt <= i) aKV[mt][nt] = __builtin_amdgcn_mfma_f32_16x16x32_bf16(afr[mt], bkv, aKV[mt][nt], 0, 0, 0);
      }
#pragma unroll
      for (int nt = 0; nt < 2; ++nt) {
        const bf16x8 bq = *(const bf16x8*)(Wqkv + (size_t)(nQ0 + nt * 16 + lc) * NE + k0 + lk);
#pragma unroll
        for (int mt = 0; mt < 4; ++mt)
          if (mt == i) aQ[nt] = __builtin_amdgcn_mfma_f32_16x16x32_bf16(afr[mt], bq, aQ[nt], 0, 0, 0);
      }
    }
    // write K -> Ks[token][h*32+d], V -> Vt[h*32+d][token], Q -> Qs (scaled)
#pragma unroll
    for (int mt = 0; mt < 4; ++mt) if (mt <= i) {
#pragma unroll
      for (int nt = 0; nt < 4; ++nt) {
        const int n = nKV + nt * 16 + lc;     // 0..511 over K|V
#pragma unroll
        for (int q = 0; q < 4; ++q) {
          const int row = mt * 16 + lr + q;
          const unsigned short hv = f2b(aKV[mt][nt][q]);
          if (n < 256) Ks[row][n] = hv;
          else Vt[n - 256][row] = hv;
        }
      }
    }
#pragma unroll
    for (int nt = 0; nt < 2; ++nt)
#pragma unroll
      for (int q = 0; q < 4; ++q)
        Qs[lr + q][nQ0 + nt * 16 + lc] = f2b(aQ[nt][q] * 0.17677669529663689f);
  }
  __syncthreads();

  // ================= Phase B: attention (wave = head) =================
  {
    const int h = wave;
    // S = Q K^T : A = Qs rows (16 q), B = Ks rows (keys), K-dim = 32
    f32x4 s[4];
    const bf16x8 qf = *(const bf16x8*)&Qs[lc][h * 32 + lk];
#pragma unroll
    for (int nt = 0; nt < 4; ++nt) {
      if (nt < ntK) {
        const bf16x8 kf = *(const bf16x8*)&Ks[nt * 16 + lc][h * 32 + lk];
        f32x4 z = {};
        s[nt] = __builtin_amdgcn_mfma_f32_16x16x32_bf16(qf, kf, z, 0, 0, 0);
      }
    }
    // causal mask + row max (rows spread: row=lr+q, key col = lane&15)
    float mx[4] = {-3e38f, -3e38f, -3e38f, -3e38f};
#pragma unroll
    for (int nt = 0; nt < 4; ++nt) if (nt < ntK) {
#pragma unroll
      for (int q = 0; q < 4; ++q) {
        const int key = nt * 16 + lc, qg = T0 + lr + q;
        float v = s[nt][q];
        v = (key <= qg) ? v : -1e30f;
        s[nt][q] = v;
        mx[q] = fmaxf(mx[q], v);
      }
    }
#pragma unroll
    for (int off = 8; off; off >>= 1)
#pragma unroll
      for (int q = 0; q < 4; ++q) mx[q] = fmaxf(mx[q], __shfl_xor(mx[q], off));
    // P = exp(S-mx) -> Ps (bf16), row sums
    float ls[4] = {};
#pragma unroll
    for (int nt = 0; nt < 4; ++nt) {
#pragma unroll
      for (int q = 0; q < 4; ++q) {
        float p = 0.0f;
        if (nt < ntK) { p = __expf(s[nt][q] - mx[q]); ls[q] += p; }
        Ps[h * 16 + lr + q][nt * 16 + lc] = f2b(p);
      }
    }
#pragma unroll
    for (int off = 8; off; off >>= 1)
#pragma unroll
      for (int q = 0; q < 4; ++q) ls[q] += __shfl_xor(ls[q], off);
    float inv[4];
#pragma unroll
    for (int q = 0; q < 4; ++q) inv[q] = 1.0f / ls[q];
    __syncthreads();   // Ps visible across lanes
    // O = P V : A = Ps rows (16 q, k=keys), B = Vt rows (dims, k=keys)
    f32x4 o[2] = {};
#pragma unroll
    for (int kt = 0; kt < 2; ++kt) {
      const bf16x8 pf = *(const bf16x8*)&Ps[h * 16 + lc][kt * 32 + lk];
#pragma unroll
      for (int dt = 0; dt < 2; ++dt) {
        const bf16x8 vf = *(const bf16x8*)&Vt[h * 32 + dt * 16 + lc][kt * 32 + lk];
        o[dt] = __builtin_amdgcn_mfma_f32_16x16x32_bf16(pf, vf, o[dt], 0, 0, 0);
      }
    }
#pragma unroll
    for (int dt = 0; dt < 2; ++dt)
#pragma unroll
      for (int q = 0; q < 4; ++q)
        atts[lr + q][h * 32 + dt * 16 + lc] = f2b(o[dt][q] * inv[q]);
  }
  __syncthreads();

  // ================= Phase C: proj + bias + residual =================
  {
    f32x4 a2[2] = {};
    const int nC0 = wave * 32;
#pragma unroll
    for (int ks = 0; ks < 8; ++ks) {
      const int k0 = ks * 32;
      const bf16x8 af = *(const bf16x8*)&atts[lc][k0 + lk];
#pragma unroll
      for (int nt = 0; nt < 2; ++nt) {
        const bf16x8 bf = *(const bf16x8*)(Wo + (size_t)(nC0 + nt * 16 + lc) * NE + k0 + lk);
        a2[nt] = __builtin_amdgcn_mfma_f32_16x16x32_bf16(af, bf, a2[nt], 0, 0, 0);
      }
    }
#pragma unroll
    for (int nt = 0; nt < 2; ++nt) {
      const int col = nC0 + nt * 16 + lc;
      const float bv = ldf(bov, (size_t)(boffo + col), isbf);
#pragma unroll
      for (int q = 0; q < 4; ++q) {
        const int row = lr + q;
        xs[row][col] = a2[nt][q] + bv + xg[(size_t)(b * 64 + T0 + row) * NE + col];
      }
    }
  }
  __syncthreads();

  // ---- LN1: 32-thread team per row; xs := ln1 out (f32), xbo := bf16 ----
  {
    const int row = tid >> 5, t5 = tid & 31;
    float s = 0.0f, s2 = 0.0f;
#pragma unroll
    for (int j = 0; j < 8; ++j) { const float v = xs[row][t5 + j * 32]; s += v; s2 += v * v; }
#pragma unroll
    for (int off = 16; off; off >>= 1) { s += __shfl_xor(s, off); s2 += __shfl_xor(s2, off); }
    const float m = s * (1.0f / NE);
    const float var = s2 * (1.0f / NE) - m * m;
    const float r = rsqrtf(var + 1e-5f);
#pragma unroll
    for (int j = 0; j < 8; ++j) {
      const int c = t5 + j * 32;
      const float o = (xs[row][c] - m) * r * ldf(g1, (size_t)(goff + c), isbf)
                      + ldf(be1, (size_t)(goff + c), isbf);
      xs[row][c] = o;
      xbo[row][c] = f2b(o);
    }
  }
  __syncthreads();

  // ================= Phase D: FFN1 (relu) =================
  {
    f32x4 a1[8] = {};
    const int nD0 = wave * 128;
#pragma unroll
    for (int ks = 0; ks < 8; ++ks) {
      const int k0 = ks * 32;
      const bf16x8 af = *(const bf16x8*)&xbo[lc][k0 + lk];
#pragma unroll
      for (int nt = 0; nt < 8; ++nt) {
        const bf16x8 bf = *(const bf16x8*)(W1 + (size_t)(nD0 + nt * 16 + lc) * NE + k0 + lk);
        a1[nt] = __builtin_amdgcn_mfma_f32_16x16x32_bf16(af, bf, a1[nt], 0, 0, 0);
      }
    }
#pragma unroll
    for (int nt = 0; nt < 8; ++nt) {
      const int col = nD0 + nt * 16 + lc;
      const float bv = ldf(b1v, (size_t)(boff1 + col), isbf);
#pragma unroll
      for (int q = 0; q < 4; ++q)
        hs[lr + q][col] = f2b(fmaxf(a1[nt][q] + bv, 0.0f));
    }
  }
  __syncthreads();

  // ================= Phase E: FFN2 + bias + residual =================
  {
    f32x4 a2[2] = {};
    const int nE0 = wave * 32;
#pragma unroll 8
    for (int ks = 0; ks < 32; ++ks) {
      const int k0 = ks * 32;
      const bf16x8 af = *(const bf16x8*)&hs[lc][k0 + lk];
#pragma unroll
      for (int nt = 0; nt < 2; ++nt) {
        const bf16x8 bf = *(const bf16x8*)(W2 + (size_t)(nE0 + nt * 16 + lc) * NF + k0 + lk);
        a2[nt] = __builtin_amdgcn_mfma_f32_16x16x32_bf16(af, bf, a2[nt], 0, 0, 0);
      }
    }
#pragma unroll
    for (int nt = 0; nt < 2; ++nt) {
      const int col = nE0 + nt * 16 + lc;
      const float bv = ldf(b2v, (size_t)(boff2 + col), isbf);
#pragma unroll
      for (int q = 0; q < 4; ++q) {
        const int row = lr + q;
        xs[row][col] = a2[nt][q] + bv + xs[row][col];
      }
    }
  }
  __syncthreads();

  // ---- LN2 + global write (x f32 + xb bf16, own 16 rows) ----
  {
    const int row = tid >> 5, t5 = tid & 31;
    float s = 0.0f, s2 = 0.0f;
#pragma unroll
    for (int j = 0; j < 8; ++j) { const float v = xs[row][t5 + j * 32]; s += v; s2 += v * v; }
#pragma unroll
    for (int off = 16; off; off >>= 1) { s += __shfl_xor(s, off); s2 += __shfl_xor(s2, off); }
    const float m = s * (1.0f / NE);
    const float var = s2 * (1.0f / NE) - m * m;
    const float r = rsqrtf(var + 1e-5f);
    const size_t gr = (size_t)(b * 64 + T0 + row) * NE;
#pragma unroll
    for (int j = 0; j < 8; ++j) {
      const int c = t5 + j * 32;
      const float o = (xs[row][c] - m) * r * ldf(g2, (size_t)(goff + c), isbf)
                      + ldf(be2, (size_t)(goff + c), isbf);
      xg[gr + c] = o;
      xbout[gr + c] = f2b(o);
    }
  }
}

// ---------- final LayerNorm (no residual): x f32 -> xf bf16 ----------
__global__ __launch_bounds__(256)
void lnf_k(const float* __restrict__ xin, const void* __restrict__ gv,
           const void* __restrict__ bv, const unsigned int* __restrict__ probe,
           unsigned short* __restrict__ xout_b)
{
  const int isbf = get_isbf(probe);
  const int tok = blockIdx.x, e = threadIdx.x;
  const float v = xin[tok * NE + e];
  float s = v, s2 = v * v;
#pragma unroll
  for (int off = 32; off > 0; off >>= 1) {
    s  += __shfl_down(s, off);
    s2 += __shfl_down(s2, off);
  }
  __shared__ float red[10];
  const int wv = e >> 6, ln = e & 63;
  if (ln == 0) { red[wv] = s; red[4 + wv] = s2; }
  __syncthreads();
  if (e == 0) {
    const float ts = red[0] + red[1] + red[2] + red[3];
    const float t2 = red[4] + red[5] + red[6] + red[7];
    const float m = ts * (1.0f / NE);
    const float var = t2 * (1.0f / NE) - m * m;
    red[8] = m; red[9] = rsqrtf(var + 1e-5f);
  }
  __syncthreads();
  const float m = red[8], r = red[9];
  const float o = (v - m) * r * ldf(gv, (size_t)e, isbf) + ldf(bv, (size_t)e, isbf);
  xout_b[tok * NE + e] = f2b(o);
}

// ---------- host orchestration ----------
extern "C" void kernel_launch(void* const* d_in, const int* in_sizes, int n_in,
                              void* d_out, int out_size, void* d_ws, size_t ws_size,
                              hipStream_t stream) {
  const int* ip = (const int*)d_in[0];
  const void* tok_emb = d_in[1];
  const void* pos_emb = d_in[2];
  const void* Wq = d_in[3];
  const void* Wk = d_in[4];
  const void* Wv = d_in[5];
  const void* Wo = d_in[6];
  const void* bo = d_in[7];
  const void* ln1_g = d_in[8];
  const void* ln1_b = d_in[9];
  const void* ln2_g = d_in[10];
  const void* ln2_b = d_in[11];
  const void* W1 = d_in[12];
  const void* b1 = d_in[13];
  const void* W2 = d_in[14];
  const void* b2 = d_in[15];
  const void* lnf_g = d_in[16];
  const void* lnf_b = d_in[17];
  const void* Wlm = d_in[18];
  const void* blm = d_in[19];
  const unsigned int* probe = (const unsigned int*)ln1_g;

  const int M = NB * NT; // 2048 tokens

  // ---- workspace layout (keeps prior footprint) ----
  unsigned short* xbA  = (unsigned short*)d_ws;            // [2048][256]
  unsigned short* xf   = xbA  + (size_t)M * NE;            // [2048][256]
  unsigned short* xbB  = xf   + (size_t)M * NE;            // [2048][256]
  unsigned short* hbuf = xbB  + (size_t)M * NE;            // [2048][1024] (unused, layout keep)
  float*          x    = (float*)(hbuf + (size_t)M * NF);  // [2048][256] f32
  unsigned short* WqkvT = (unsigned short*)(x + (size_t)M * NE); // [L][768][256]
  unsigned short* WoT  = WqkvT + (size_t)NL * 768 * NE;    // [L][256][256]
  unsigned short* W1T  = WoT   + (size_t)NL * NE * NE;     // [L][1024][256]
  unsigned short* W2T  = W1T   + (size_t)NL * NF * NE;     // [L][256][1024]
  unsigned short* WlmT = W2T   + (size_t)NL * NE * NF;     // [NVPAD][256]

  // ---- weight transposes (2 launches) ----
  dim3 tb(32, 8, 1);
  transpose_weights_k<<<dim3(768, 1, NL), tb, 0, stream>>>(
      Wq, Wk, Wv, Wo, W1, W2, probe, WqkvT, WoT, W1T, W2T);
  transpose_k<<<dim3((NV + 31) / 32, NE / 32, 1), tb, 0, stream>>>(Wlm, WlmT, probe, NE, NV);

  // ---- embedding ----
  embed_k<<<dim3(M), dim3(256), 0, stream>>>(ip, tok_emb, pos_emb, probe, x, xbA);

  // ---- transformer layers: one kernel per layer ----
  for (int l = 0; l < NL; ++l) {
    const unsigned short* xin = (l & 1) ? xbB : xbA;
    unsigned short* xout      = (l & 1) ? xbA : xbB;
    layer_k<<<dim3(4, NB), dim3(512), 0, stream>>>(
        xin, xout, x,
        WqkvT + (size_t)l * 768 * NE, WoT + (size_t)l * NE * NE,
        W1T + (size_t)l * NF * NE, W2T + (size_t)l * NE * NF,
        bo, b1, b2, ln1_g, ln1_b, ln2_g, ln2_b, probe,
        l * NE, l * NF, l * NE, l * NE);
  }

  // ---- final LN -> xf (bf16) ----
  lnf_k<<<dim3(M), dim3(256), 0, stream>>>(x, lnf_g, lnf_b, probe, xf);

  // ---- LM head: xf [2048,256] x WlmT + blm -> out (dtype-adaptive) ----
  gemm_bt<128, 128, 64, 64, 64, true, false, 2><<<dim3(NVPAD / 128, M / 128), dim3(256), 0, stream>>>(
      xf, WlmT, blm, 0, probe, d_out, M, NV, NE, NV);
}